// Round 1
// baseline (368.425 us; speedup 1.0000x reference)
//
#include <hip/hip_runtime.h>
#include <hip/hip_bf16.h>
#include <cstdint>
#include <cstddef>

#define B_ 2
#define T_ 2048
#define C_ 1024
#define H_ 16
#define D_ 64
#define BT_ (B_*T_)

typedef __bf16 bf16;
typedef __bf16 bf16x4 __attribute__((ext_vector_type(4)));
typedef __bf16 bf16x8 __attribute__((ext_vector_type(8)));
typedef float f32x4 __attribute__((ext_vector_type(4)));

// ---------------------------------------------------------------- cast f32->bf16
__global__ __launch_bounds__(256) void cast_f32_bf16(const float* __restrict__ in,
                                                     bf16* __restrict__ out, int n) {
  int stride = gridDim.x * blockDim.x;
  for (int i = blockIdx.x * blockDim.x + threadIdx.x; i * 4 < n; i += stride) {
    float4 v = *reinterpret_cast<const float4*>(in + (size_t)i * 4);
    bf16x4 o;
    o[0] = (bf16)v.x; o[1] = (bf16)v.y; o[2] = (bf16)v.z; o[3] = (bf16)v.w;
    *reinterpret_cast<bf16x4*>(out + (size_t)i * 4) = o;
  }
}

// ---------------------------------------------------------------- GEMM: C = A @ B^T + bias
// A [M,K] bf16 row-major, Bm [N,K] bf16 row-major (nn.Linear weight), bias [N] f32.
// 128x128 tile, BK=32, 256 threads = 4 waves (2x2), each wave 64x64 = 4x4 frags.
template<typename OutT>
__global__ __launch_bounds__(256) void gemm_bt(const bf16* __restrict__ A,
                                               const bf16* __restrict__ Bm,
                                               const float* __restrict__ bias,
                                               OutT* __restrict__ Cout,
                                               int M, int N, int K) {
  __shared__ bf16 As[128 * 32];
  __shared__ bf16 Bs[128 * 32];
  const int tid = threadIdx.x;
  const int wid = tid >> 6, lane = tid & 63;
  const int grp = lane >> 4, li = lane & 15;
  const int wr = wid >> 1, wc = wid & 1;
  const int m0 = blockIdx.y * 128, n0 = blockIdx.x * 128;

  f32x4 acc[4][4] = {};

  const int srow = lane >> 2;         // 0..15 within a wave's 16-row stripe
  const int scol = (lane & 3) * 8;    // 0,8,16,24

  for (int k0 = 0; k0 < K; k0 += 32) {
#pragma unroll
    for (int p = 0; p < 2; ++p) {
      const int rbase = (p * 4 + wid) * 16;
      const bf16* ga = A + (size_t)(m0 + rbase + srow) * K + (k0 + scol);
      const bf16* gb = Bm + (size_t)(n0 + rbase + srow) * K + (k0 + scol);
      bf16* la = As + (p * 4 + wid) * 512;   // wave-uniform LDS base; HW adds lane*16B
      bf16* lb = Bs + (p * 4 + wid) * 512;
      __builtin_amdgcn_global_load_lds((__attribute__((address_space(1))) void*)ga,
                                       (__attribute__((address_space(3))) void*)la, 16, 0, 0);
      __builtin_amdgcn_global_load_lds((__attribute__((address_space(1))) void*)gb,
                                       (__attribute__((address_space(3))) void*)lb, 16, 0, 0);
    }
    __syncthreads();   // drains vmcnt before barrier (compiler-inserted)

    bf16x8 af[4], bfr[4];
#pragma unroll
    for (int m = 0; m < 4; ++m)
      af[m] = *reinterpret_cast<const bf16x8*>(&As[(wr * 64 + m * 16 + li) * 32 + grp * 8]);
#pragma unroll
    for (int n = 0; n < 4; ++n)
      bfr[n] = *reinterpret_cast<const bf16x8*>(&Bs[(wc * 64 + n * 16 + li) * 32 + grp * 8]);
#pragma unroll
    for (int m = 0; m < 4; ++m)
#pragma unroll
      for (int n = 0; n < 4; ++n)
        acc[m][n] = __builtin_amdgcn_mfma_f32_16x16x32_bf16(af[m], bfr[n], acc[m][n], 0, 0, 0);
    __syncthreads();   // protect LDS before next stage overwrites
  }

  float bcol[4];
#pragma unroll
  for (int n = 0; n < 4; ++n) bcol[n] = bias[n0 + wc * 64 + n * 16 + li];
#pragma unroll
  for (int m = 0; m < 4; ++m) {
#pragma unroll
    for (int n = 0; n < 4; ++n) {
      const int col = n0 + wc * 64 + n * 16 + li;
#pragma unroll
      for (int j = 0; j < 4; ++j) {
        const int row = m0 + wr * 64 + m * 16 + grp * 4 + j;
        float v = acc[m][n][j] + bcol[n];
        Cout[(size_t)row * N + col] = (OutT)v;
      }
    }
  }
}

// ---------------------------------------------------------------- flash attention w/ ALiBi
// Q,K,V: [B*T, C] bf16 (head h occupies cols h*64..h*64+63). Y: same layout, bf16.
// Grid: (T/64, B*H). Block: 256 = 4 waves; wave w owns q rows q0+w*16..+15.
__global__ __launch_bounds__(256) void attn_kernel(const bf16* __restrict__ Q,
                                                   const bf16* __restrict__ Km,
                                                   const bf16* __restrict__ V,
                                                   bf16* __restrict__ Y) {
  __shared__ bf16 Ks[64 * 72];      // [kv][d] padded stride 72
  __shared__ bf16 Vt[64 * 72];      // [d][kv] padded stride 72
  __shared__ bf16 Ps[4 * 16 * 72];  // per-wave P scratch [wave*16+q][kv]

  const int tid = threadIdx.x;
  const int wid = tid >> 6, lane = tid & 63;
  const int grp = lane >> 4, li = lane & 15;
  const int qt = blockIdx.x, bh = blockIdx.y;
  const int b = bh >> 4, h = bh & 15;
  const int q0 = qt * 64;
  const float slope = exp2f(-0.5f * (float)(h + 1));
  const float scale = 0.125f;  // 1/sqrt(64)

  // Q fragments: A-operand layout (row=li, k=8*grp+j), 2 chunks over D=64
  bf16x8 qf[2];
  {
    const bf16* qrow = Q + (size_t)(b * T_ + q0 + wid * 16 + li) * C_ + h * D_;
    qf[0] = *reinterpret_cast<const bf16x8*>(qrow + grp * 8);
    qf[1] = *reinterpret_cast<const bf16x8*>(qrow + 32 + grp * 8);
  }

  f32x4 oacc[4] = {};
  float mrow[4] = {-__builtin_inff(), -__builtin_inff(), -__builtin_inff(), -__builtin_inff()};
  float lrow[4] = {0.f, 0.f, 0.f, 0.f};
  const int qrow_base = q0 + wid * 16 + grp * 4;  // + j gives this lane's q rows

  for (int kv0 = 0; kv0 <= q0; kv0 += 64) {
    // ---- stage K tile and V^T tile
#pragma unroll
    for (int p = 0; p < 2; ++p) {
      const int e = (p * 256 + tid) * 8;
      const int r = e >> 6, c = e & 63;
      const size_t grow = (size_t)(b * T_ + kv0 + r) * C_ + h * D_ + c;
      bf16x8 k8 = *reinterpret_cast<const bf16x8*>(Km + grow);
      *reinterpret_cast<bf16x8*>(&Ks[r * 72 + c]) = k8;
      bf16x8 v8 = *reinterpret_cast<const bf16x8*>(V + grow);
#pragma unroll
      for (int j = 0; j < 8; ++j) Vt[(c + j) * 72 + r] = v8[j];
    }
    __syncthreads();

    // ---- S = Q @ K^T : 4 kv-col frags x 2 d-chunks
    f32x4 s[4] = {};
#pragma unroll
    for (int n = 0; n < 4; ++n) {
      bf16x8 kf0 = *reinterpret_cast<const bf16x8*>(&Ks[(n * 16 + li) * 72 + grp * 8]);
      bf16x8 kf1 = *reinterpret_cast<const bf16x8*>(&Ks[(n * 16 + li) * 72 + 32 + grp * 8]);
      s[n] = __builtin_amdgcn_mfma_f32_16x16x32_bf16(qf[0], kf0, s[n], 0, 0, 0);
      s[n] = __builtin_amdgcn_mfma_f32_16x16x32_bf16(qf[1], kf1, s[n], 0, 0, 0);
    }

    // ---- scale + ALiBi + causal mask + online softmax
    float pv[4][4];  // [n][j]
#pragma unroll
    for (int j = 0; j < 4; ++j) {
      const int qi = qrow_base + j;
      float rm = -1e30f;
#pragma unroll
      for (int n = 0; n < 4; ++n) {
        const int kj = kv0 + n * 16 + li;
        float sv = s[n][j] * scale;
        sv = (kj <= qi) ? (sv - slope * (float)(qi - kj)) : -1e30f;
        pv[n][j] = sv;
        rm = fmaxf(rm, sv);
      }
#pragma unroll
      for (int off = 8; off >= 1; off >>= 1)
        rm = fmaxf(rm, __shfl_xor(rm, off, 64));
      const float mnew = fmaxf(mrow[j], rm);
      const float alpha = __expf(mrow[j] - mnew);
      mrow[j] = mnew;
      float rs = 0.f;
#pragma unroll
      for (int n = 0; n < 4; ++n) {
        float p = __expf(pv[n][j] - mnew);
        pv[n][j] = p;
        rs += p;
      }
#pragma unroll
      for (int off = 8; off >= 1; off >>= 1)
        rs += __shfl_xor(rs, off, 64);
      lrow[j] = lrow[j] * alpha + rs;
#pragma unroll
      for (int n = 0; n < 4; ++n) oacc[n][j] *= alpha;
    }

    // ---- P -> per-wave LDS (C/D layout -> A layout round-trip)
#pragma unroll
    for (int n = 0; n < 4; ++n)
#pragma unroll
      for (int j = 0; j < 4; ++j)
        Ps[(wid * 16 + grp * 4 + j) * 72 + n * 16 + li] = (bf16)pv[n][j];
    asm volatile("s_waitcnt lgkmcnt(0)" ::: "memory");

    // ---- O += P @ V
#pragma unroll
    for (int kc = 0; kc < 2; ++kc) {
      bf16x8 pa = *reinterpret_cast<const bf16x8*>(&Ps[(wid * 16 + li) * 72 + kc * 32 + grp * 8]);
#pragma unroll
      for (int nd = 0; nd < 4; ++nd) {
        bf16x8 vf = *reinterpret_cast<const bf16x8*>(&Vt[(nd * 16 + li) * 72 + kc * 32 + grp * 8]);
        oacc[nd] = __builtin_amdgcn_mfma_f32_16x16x32_bf16(pa, vf, oacc[nd], 0, 0, 0);
      }
    }
    __syncthreads();   // before next kv tile overwrites Ks/Vt
  }

  // ---- epilogue: O / l -> Y
#pragma unroll
  for (int nd = 0; nd < 4; ++nd) {
#pragma unroll
    for (int j = 0; j < 4; ++j) {
      float v = oacc[nd][j] / lrow[j];
      Y[(size_t)(b * T_ + qrow_base + j) * C_ + h * D_ + nd * 16 + li] = (bf16)v;
    }
  }
}

// ---------------------------------------------------------------- launch
extern "C" void kernel_launch(void* const* d_in, const int* in_sizes, int n_in,
                              void* d_out, int out_size, void* d_ws, size_t ws_size,
                              hipStream_t stream) {
  const float* x  = (const float*)d_in[0];
  const float* Wq = (const float*)d_in[1];
  const float* bq = (const float*)d_in[2];
  const float* Wk = (const float*)d_in[3];
  const float* bk = (const float*)d_in[4];
  const float* Wv = (const float*)d_in[5];
  const float* bv = (const float*)d_in[6];
  const float* Wo = (const float*)d_in[7];
  const float* bo = (const float*)d_in[8];
  float* out = (float*)d_out;

  char* ws = (char*)d_ws;
  bf16* xb  = (bf16*)ws; ws += (size_t)BT_ * C_ * 2;
  bf16* wqb = (bf16*)ws; ws += (size_t)C_ * C_ * 2;
  bf16* wkb = (bf16*)ws; ws += (size_t)C_ * C_ * 2;
  bf16* wvb = (bf16*)ws; ws += (size_t)C_ * C_ * 2;
  bf16* wob = (bf16*)ws; ws += (size_t)C_ * C_ * 2;
  bf16* qb  = (bf16*)ws; ws += (size_t)BT_ * C_ * 2;
  bf16* kb  = (bf16*)ws; ws += (size_t)BT_ * C_ * 2;
  bf16* vb  = (bf16*)ws; ws += (size_t)BT_ * C_ * 2;
  bf16* yb  = (bf16*)ws; ws += (size_t)BT_ * C_ * 2;

  auto cast = [&](const float* src, bf16* dst, int n) {
    int thr = n / 4;
    int blocks = (thr + 255) / 256;
    if (blocks > 4096) blocks = 4096;
    cast_f32_bf16<<<dim3(blocks), dim3(256), 0, stream>>>(src, dst, n);
  };
  cast(x,  xb,  BT_ * C_);
  cast(Wq, wqb, C_ * C_);
  cast(Wk, wkb, C_ * C_);
  cast(Wv, wvb, C_ * C_);
  cast(Wo, wob, C_ * C_);

  dim3 ggrid(C_ / 128, BT_ / 128);  // (8, 32)
  gemm_bt<bf16><<<ggrid, dim3(256), 0, stream>>>(xb, wqb, bq, qb, BT_, C_, C_);
  gemm_bt<bf16><<<ggrid, dim3(256), 0, stream>>>(xb, wkb, bk, kb, BT_, C_, C_);
  gemm_bt<bf16><<<ggrid, dim3(256), 0, stream>>>(xb, wvb, bv, vb, BT_, C_, C_);

  attn_kernel<<<dim3(T_ / 64, B_ * H_), dim3(256), 0, stream>>>(qb, kb, vb, yb);

  gemm_bt<float><<<ggrid, dim3(256), 0, stream>>>(yb, wob, bo, out, BT_, C_, C_);
}

// Round 2
// 299.231 us; speedup vs baseline: 1.2312x; 1.2312x over previous
//
#include <hip/hip_runtime.h>
#include <hip/hip_bf16.h>
#include <cstdint>
#include <cstddef>

#define B_ 2
#define T_ 2048
#define C_ 1024
#define H_ 16
#define D_ 64
#define BT_ (B_*T_)
#define QKV_S 3072

typedef __bf16 bf16;
typedef __bf16 bf16x4 __attribute__((ext_vector_type(4)));
typedef __bf16 bf16x8 __attribute__((ext_vector_type(8)));
typedef float f32x4 __attribute__((ext_vector_type(4)));

// ---------------------------------------------------------------- cast f32->bf16
__global__ __launch_bounds__(256) void cast_f32_bf16(const float* __restrict__ in,
                                                     bf16* __restrict__ out, int n) {
  int stride = gridDim.x * blockDim.x;
  for (int i = blockIdx.x * blockDim.x + threadIdx.x; i * 4 < n; i += stride) {
    float4 v = *reinterpret_cast<const float4*>(in + (size_t)i * 4);
    bf16x4 o;
    o[0] = (bf16)v.x; o[1] = (bf16)v.y; o[2] = (bf16)v.z; o[3] = (bf16)v.w;
    *reinterpret_cast<bf16x4*>(out + (size_t)i * 4) = o;
  }
}

// ---------------------------------------------------------------- GEMM: C = A @ B^T + bias
// A [M,K] bf16 row-major, Bm [N,K] bf16 row-major, bias [N] f32.
// 128x128 tile, BK=32, 256 threads = 4 waves (2x2), each wave 64x64 = 4x4 frags.
template<typename OutT>
__global__ __launch_bounds__(256) void gemm_bt(const bf16* __restrict__ A,
                                               const bf16* __restrict__ Bm,
                                               const float* __restrict__ bias,
                                               OutT* __restrict__ Cout,
                                               int M, int N, int K) {
  __shared__ bf16 As[128 * 32];
  __shared__ bf16 Bs[128 * 32];
  const int tid = threadIdx.x;
  const int wid = tid >> 6, lane = tid & 63;
  const int grp = lane >> 4, li = lane & 15;
  const int wr = wid >> 1, wc = wid & 1;
  const int m0 = blockIdx.y * 128, n0 = blockIdx.x * 128;

  f32x4 acc[4][4] = {};

  const int srow = lane >> 2;         // 0..15
  const int scol = (lane & 3) * 8;    // 0,8,16,24

  for (int k0 = 0; k0 < K; k0 += 32) {
#pragma unroll
    for (int p = 0; p < 2; ++p) {
      const int rbase = (p * 4 + wid) * 16;
      const bf16* ga = A + (size_t)(m0 + rbase + srow) * K + (k0 + scol);
      const bf16* gb = Bm + (size_t)(n0 + rbase + srow) * K + (k0 + scol);
      bf16* la = As + (p * 4 + wid) * 512;
      bf16* lb = Bs + (p * 4 + wid) * 512;
      __builtin_amdgcn_global_load_lds((__attribute__((address_space(1))) void*)ga,
                                       (__attribute__((address_space(3))) void*)la, 16, 0, 0);
      __builtin_amdgcn_global_load_lds((__attribute__((address_space(1))) void*)gb,
                                       (__attribute__((address_space(3))) void*)lb, 16, 0, 0);
    }
    __syncthreads();

    bf16x8 af[4], bfr[4];
#pragma unroll
    for (int m = 0; m < 4; ++m)
      af[m] = *reinterpret_cast<const bf16x8*>(&As[(wr * 64 + m * 16 + li) * 32 + grp * 8]);
#pragma unroll
    for (int n = 0; n < 4; ++n)
      bfr[n] = *reinterpret_cast<const bf16x8*>(&Bs[(wc * 64 + n * 16 + li) * 32 + grp * 8]);
#pragma unroll
    for (int m = 0; m < 4; ++m)
#pragma unroll
      for (int n = 0; n < 4; ++n)
        acc[m][n] = __builtin_amdgcn_mfma_f32_16x16x32_bf16(af[m], bfr[n], acc[m][n], 0, 0, 0);
    __syncthreads();
  }

  float bcol[4];
#pragma unroll
  for (int n = 0; n < 4; ++n) bcol[n] = bias[n0 + wc * 64 + n * 16 + li];
#pragma unroll
  for (int m = 0; m < 4; ++m) {
#pragma unroll
    for (int n = 0; n < 4; ++n) {
      const int col = n0 + wc * 64 + n * 16 + li;
#pragma unroll
      for (int j = 0; j < 4; ++j) {
        const int row = m0 + wr * 64 + m * 16 + grp * 4 + j;
        float v = acc[m][n][j] + bcol[n];
        Cout[(size_t)row * N + col] = (OutT)v;
      }
    }
  }
}

// ---------------------------------------------------------------- V transpose: qkv v-part -> Vt[bh][d][T]
__global__ __launch_bounds__(256) void transpose_v(const bf16* __restrict__ qkv,
                                                   bf16* __restrict__ Vt) {
  __shared__ bf16 tile[64 * 72];
  const int tid = threadIdx.x;
  const int t0 = blockIdx.x * 64, bh = blockIdx.y;
  const int b = bh >> 4, h = bh & 15;
#pragma unroll
  for (int p = 0; p < 2; ++p) {
    int idx = p * 256 + tid;
    int r = idx >> 3, c = (idx & 7) * 8;
    bf16x8 v = *reinterpret_cast<const bf16x8*>(qkv + (size_t)(b * T_ + t0 + r) * QKV_S + 2 * C_ + h * D_ + c);
    *reinterpret_cast<bf16x8*>(&tile[r * 72 + c]) = v;
  }
  __syncthreads();
#pragma unroll
  for (int p = 0; p < 2; ++p) {
    int idx = p * 256 + tid;
    int d = idx >> 3, tc = (idx & 7) * 8;
    bf16x8 o;
#pragma unroll
    for (int j = 0; j < 8; ++j) o[j] = tile[(tc + j) * 72 + d];
    *reinterpret_cast<bf16x8*>(Vt + ((size_t)bh * D_ + d) * T_ + t0 + tc) = o;
  }
}

// ---------------------------------------------------------------- flash attention w/ ALiBi
// qkv: [B*T, 3072] bf16 (q at h*64, k at 1024+h*64). Vt: [B*H, 64, T] bf16. Y: [B*T, 1024] bf16.
// Grid: (T/64, B*H). Block: 256 = 4 waves; wave w owns q rows q0+w*16..+15.
// K/V LDS tiles are linear [64][64] with XOR-swizzle (byte ^= (row&7)<<4) applied on the
// GLOBAL source during global_load_lds staging and on every read (rule: both-sides-or-neither).
__global__ __launch_bounds__(256) void attn_kernel(const bf16* __restrict__ qkv,
                                                   const bf16* __restrict__ Vt,
                                                   bf16* __restrict__ Y) {
  __shared__ bf16 Ks[64 * 64];
  __shared__ bf16 Vs[64 * 64];
  __shared__ bf16 Ps[4 * 16 * 64];

  const int tid = threadIdx.x;
  const int wid = tid >> 6, lane = tid & 63;
  const int grp = lane >> 4, li = lane & 15;
  const int qt = gridDim.x - 1 - blockIdx.x;  // heavy blocks first
  const int bh = blockIdx.y;
  const int b = bh >> 4, h = bh & 15;
  const int q0 = qt * 64;
  const float slope = exp2f(-0.5f * (float)(h + 1));
  const float scale = 0.125f;  // 1/sqrt(64)

  // Q fragments: A-operand layout (row=li, k=8*grp+j), 2 chunks over D=64
  bf16x8 qf[2];
  {
    const bf16* qrow = qkv + (size_t)(b * T_ + q0 + wid * 16 + li) * QKV_S + h * D_;
    qf[0] = *reinterpret_cast<const bf16x8*>(qrow + grp * 8);
    qf[1] = *reinterpret_cast<const bf16x8*>(qrow + 32 + grp * 8);
  }

  f32x4 oacc[4] = {};
  float mrow[4] = {-__builtin_inff(), -__builtin_inff(), -__builtin_inff(), -__builtin_inff()};
  float lrow[4] = {0.f, 0.f, 0.f, 0.f};
  const int qrow_base = q0 + wid * 16 + grp * 4;

  const int srow = lane >> 3;             // 0..7 == row&7 within 8-row stripe
  const int swzb = ((lane & 7) * 16) ^ (srow << 4);  // pre-swizzled byte col in global row
  const int rsw = (li & 7) << 3;          // element XOR for fragment reads

  for (int kv0 = 0; kv0 <= q0; kv0 += 64) {
    // ---- stage K tile and V^T tile (linear LDS dest, inverse-swizzled global source)
#pragma unroll
    for (int p = 0; p < 2; ++p) {
      const int rbase = p * 32 + wid * 8;
      const int row = rbase + srow;
      const bf16* gk = qkv + (size_t)(b * T_ + kv0 + row) * QKV_S + C_ + h * D_ + (swzb >> 1);
      const bf16* gv = Vt + ((size_t)bh * D_ + row) * T_ + kv0 + (swzb >> 1);
      __builtin_amdgcn_global_load_lds((__attribute__((address_space(1))) void*)gk,
                                       (__attribute__((address_space(3))) void*)(Ks + rbase * 64), 16, 0, 0);
      __builtin_amdgcn_global_load_lds((__attribute__((address_space(1))) void*)gv,
                                       (__attribute__((address_space(3))) void*)(Vs + rbase * 64), 16, 0, 0);
    }
    __syncthreads();

    // ---- S = Q @ K^T : 4 kv-col frags x 2 d-chunks (swizzled reads)
    f32x4 s[4] = {};
#pragma unroll
    for (int n = 0; n < 4; ++n) {
      const bf16* kr = Ks + (n * 16 + li) * 64;
      bf16x8 kf0 = *reinterpret_cast<const bf16x8*>(kr + ((grp * 8) ^ rsw));
      bf16x8 kf1 = *reinterpret_cast<const bf16x8*>(kr + ((32 + grp * 8) ^ rsw));
      s[n] = __builtin_amdgcn_mfma_f32_16x16x32_bf16(qf[0], kf0, s[n], 0, 0, 0);
      s[n] = __builtin_amdgcn_mfma_f32_16x16x32_bf16(qf[1], kf1, s[n], 0, 0, 0);
    }

    // ---- scale + ALiBi + causal mask + online softmax
    float pv[4][4];  // [n][j]
#pragma unroll
    for (int j = 0; j < 4; ++j) {
      const int qi = qrow_base + j;
      float rm = -1e30f;
#pragma unroll
      for (int n = 0; n < 4; ++n) {
        const int kj = kv0 + n * 16 + li;
        float sv = s[n][j] * scale;
        sv = (kj <= qi) ? (sv - slope * (float)(qi - kj)) : -1e30f;
        pv[n][j] = sv;
        rm = fmaxf(rm, sv);
      }
#pragma unroll
      for (int off = 8; off >= 1; off >>= 1)
        rm = fmaxf(rm, __shfl_xor(rm, off, 64));
      const float mnew = fmaxf(mrow[j], rm);
      const float alpha = __expf(mrow[j] - mnew);
      mrow[j] = mnew;
      float rs = 0.f;
#pragma unroll
      for (int n = 0; n < 4; ++n) {
        float p = __expf(pv[n][j] - mnew);
        pv[n][j] = p;
        rs += p;
      }
#pragma unroll
      for (int off = 8; off >= 1; off >>= 1)
        rs += __shfl_xor(rs, off, 64);
      lrow[j] = lrow[j] * alpha + rs;
#pragma unroll
      for (int n = 0; n < 4; ++n) oacc[n][j] *= alpha;
    }

    // ---- P -> per-wave LDS (swizzled), C/D layout -> A layout
#pragma unroll
    for (int n = 0; n < 4; ++n)
#pragma unroll
      for (int j = 0; j < 4; ++j) {
        const int q = grp * 4 + j;
        Ps[wid * 1024 + q * 64 + ((n * 16 + li) ^ ((q & 7) << 3))] = (bf16)pv[n][j];
      }
    asm volatile("s_waitcnt lgkmcnt(0)" ::: "memory");

    // ---- O += P @ V (swizzled reads)
#pragma unroll
    for (int kc = 0; kc < 2; ++kc) {
      bf16x8 pa = *reinterpret_cast<const bf16x8*>(Ps + wid * 1024 + li * 64 + ((kc * 32 + grp * 8) ^ rsw));
#pragma unroll
      for (int nd = 0; nd < 4; ++nd) {
        bf16x8 vf = *reinterpret_cast<const bf16x8*>(Vs + (nd * 16 + li) * 64 + ((kc * 32 + grp * 8) ^ rsw));
        oacc[nd] = __builtin_amdgcn_mfma_f32_16x16x32_bf16(pa, vf, oacc[nd], 0, 0, 0);
      }
    }
    __syncthreads();
  }

  // ---- epilogue: O / l -> Y
  float rinv[4];
#pragma unroll
  for (int j = 0; j < 4; ++j) rinv[j] = 1.f / lrow[j];
#pragma unroll
  for (int nd = 0; nd < 4; ++nd) {
#pragma unroll
    for (int j = 0; j < 4; ++j) {
      float v = oacc[nd][j] * rinv[j];
      Y[(size_t)(b * T_ + qrow_base + j) * C_ + h * D_ + nd * 16 + li] = (bf16)v;
    }
  }
}

// ---------------------------------------------------------------- launch
extern "C" void kernel_launch(void* const* d_in, const int* in_sizes, int n_in,
                              void* d_out, int out_size, void* d_ws, size_t ws_size,
                              hipStream_t stream) {
  const float* x  = (const float*)d_in[0];
  const float* Wq = (const float*)d_in[1];
  const float* bq = (const float*)d_in[2];
  const float* Wk = (const float*)d_in[3];
  const float* bk = (const float*)d_in[4];
  const float* Wv = (const float*)d_in[5];
  const float* bv = (const float*)d_in[6];
  const float* Wo = (const float*)d_in[7];
  const float* bo = (const float*)d_in[8];
  float* out = (float*)d_out;

  char* ws = (char*)d_ws;
  bf16* xb    = (bf16*)ws; ws += (size_t)BT_ * C_ * 2;          // 8 MB (reused as yb)
  bf16* wqkvb = (bf16*)ws; ws += (size_t)3 * C_ * C_ * 2;       // 6 MB
  bf16* wob   = (bf16*)ws; ws += (size_t)C_ * C_ * 2;           // 2 MB
  bf16* qkvb  = (bf16*)ws; ws += (size_t)BT_ * QKV_S * 2;       // 24 MB
  bf16* vtb   = (bf16*)ws; ws += (size_t)B_ * H_ * D_ * T_ * 2; // 8 MB
  float* bqkv = (float*)ws; ws += (size_t)3 * C_ * 4;           // 12 KB
  bf16* yb    = xb;  // x dead after QKV GEMM

  hipMemcpyAsync(bqkv,          bq, C_ * 4, hipMemcpyDeviceToDevice, stream);
  hipMemcpyAsync(bqkv + C_,     bk, C_ * 4, hipMemcpyDeviceToDevice, stream);
  hipMemcpyAsync(bqkv + 2 * C_, bv, C_ * 4, hipMemcpyDeviceToDevice, stream);

  auto cast = [&](const float* src, bf16* dst, int n) {
    int thr = n / 4;
    int blocks = (thr + 255) / 256;
    if (blocks > 4096) blocks = 4096;
    cast_f32_bf16<<<dim3(blocks), dim3(256), 0, stream>>>(src, dst, n);
  };
  cast(x,  xb,  BT_ * C_);
  cast(Wq, wqkvb,             C_ * C_);
  cast(Wk, wqkvb + C_ * C_,   C_ * C_);
  cast(Wv, wqkvb + 2 * C_ * C_, C_ * C_);
  cast(Wo, wob, C_ * C_);

  // fused QKV projection: [BT,1024] @ [3072,1024]^T -> [BT,3072]
  gemm_bt<bf16><<<dim3(QKV_S / 128, BT_ / 128), dim3(256), 0, stream>>>(xb, wqkvb, bqkv, qkvb, BT_, QKV_S, C_);

  transpose_v<<<dim3(T_ / 64, B_ * H_), dim3(256), 0, stream>>>(qkvb, vtb);

  attn_kernel<<<dim3(T_ / 64, B_ * H_), dim3(256), 0, stream>>>(qkvb, vtb, yb);

  gemm_bt<float><<<dim3(C_ / 128, BT_ / 128), dim3(256), 0, stream>>>(yb, wob, bo, out, BT_, C_, C_);
}